// Round 2
// baseline (666.959 us; speedup 1.0000x reference)
//
#include <hip/hip_runtime.h>
#include <hip/hip_bf16.h>
#include <math.h>

#define H 1024
#define L 128
#define B 256
#define V 32000

typedef __attribute__((ext_vector_type(8))) short bf16x8;
typedef __attribute__((ext_vector_type(4))) float f32x4;

static __device__ __forceinline__ ushort f2bf(float f) {
    unsigned int u = __float_as_uint(f);
    u += 0x7fffu + ((u >> 16) & 1u);   // RNE (finite inputs)
    return (ushort)(u >> 16);
}

// ---------------------------------------------------------------------------
// Kernel 1: embedding gather + attention logits + softmax + weighted sum.
// 1024 threads/block (16 waves) for memory-latency hiding on the enc stream.
// ---------------------------------------------------------------------------
__global__ __launch_bounds__(1024) void attn_kernel(
    const int* __restrict__ input_ids,
    const float* __restrict__ hidden,
    const float* __restrict__ enc,
    const float* __restrict__ emb_table,
    const float* __restrict__ attn_w,
    const float* __restrict__ attn_b,
    ushort* __restrict__ xcat_b16,         // (B, 2H) bf16
    ushort* __restrict__ h0_b16,           // (B, H) bf16
    float* __restrict__ attn_weights_out)  // (B, L)
{
    __shared__ float s_e[H];
    __shared__ float s_h[H];
    __shared__ float s_w[L];
    __shared__ float s_r[4];
    __shared__ float4 s_pac[3 * 256];      // 12 KB partial-sum reduce

    const int b = blockIdx.x;
    const int tid = threadIdx.x;

    // load emb row + hidden row into LDS, emit bf16 copies
    if (tid < 256) {
        const int id = input_ids[b];
        float4 ev = ((const float4*)(emb_table + (size_t)id * H))[tid];
        ((float4*)s_e)[tid] = ev;
        uint2 p;
        p.x = (unsigned)f2bf(ev.x) | ((unsigned)f2bf(ev.y) << 16);
        p.y = (unsigned)f2bf(ev.z) | ((unsigned)f2bf(ev.w) << 16);
        *(uint2*)(xcat_b16 + (size_t)b * 2 * H + tid * 4) = p;
    } else if (tid < 512) {
        const int t = tid - 256;
        float4 hv = ((const float4*)(hidden + (size_t)b * H))[t];
        ((float4*)s_h)[t] = hv;
        uint2 q;
        q.x = (unsigned)f2bf(hv.x) | ((unsigned)f2bf(hv.y) << 16);
        q.y = (unsigned)f2bf(hv.z) | ((unsigned)f2bf(hv.w) << 16);
        *(uint2*)(h0_b16 + (size_t)b * H + t * 4) = q;
    }
    __syncthreads();

    // logits: 8 threads per l-row, strided float4 so 8 lanes coalesce to 128B
    {
        const int ll = tid >> 3;   // 0..127
        const int p = tid & 7;
        const float4* wv = (const float4*)(attn_w + (size_t)ll * (2 * H)) + p;
        const float4* se4 = (const float4*)s_e + p;
        const float4* sh4 = (const float4*)s_h + p;
        float acc = 0.f;
#pragma unroll 8
        for (int k = 0; k < 32; ++k) {
            float4 a = wv[k * 8];
            float4 s = se4[k * 8];
            acc += a.x * s.x + a.y * s.y + a.z * s.z + a.w * s.w;
        }
#pragma unroll 8
        for (int k = 0; k < 32; ++k) {
            float4 a = wv[256 + k * 8];
            float4 s = sh4[k * 8];
            acc += a.x * s.x + a.y * s.y + a.z * s.z + a.w * s.w;
        }
        acc += __shfl_xor(acc, 1);
        acc += __shfl_xor(acc, 2);
        acc += __shfl_xor(acc, 4);
        if (p == 0) s_w[ll] = acc + attn_b[ll];
    }
    __syncthreads();

    // softmax over s_w[0..127] (first 2 waves)
    const int lane = tid & 63;
    if (tid < 128) {
        float v = s_w[tid];
        for (int off = 32; off; off >>= 1) v = fmaxf(v, __shfl_xor(v, off));
        if (lane == 0) s_r[tid >> 6] = v;
    }
    __syncthreads();
    if (tid < 128) {
        const float m = fmaxf(s_r[0], s_r[1]);
        float e = __expf(s_w[tid] - m);
        float sv = e;
        for (int off = 32; off; off >>= 1) sv += __shfl_xor(sv, off);
        if (lane == 0) s_r[2 + (tid >> 6)] = sv;
        s_w[tid] = e;
    }
    __syncthreads();
    if (tid < 128) {
        const float inv = 1.f / (s_r[2] + s_r[3]);
        const float wv = s_w[tid] * inv;
        s_w[tid] = wv;
        attn_weights_out[(size_t)b * L + tid] = wv;
    }
    __syncthreads();

    // attn_applied: 4 l-groups x 256 float4 columns, LDS tree reduce
    {
        const int grp = tid >> 8;     // 0..3 -> l range [grp*32, grp*32+32)
        const int c = tid & 255;      // float4 column
        const float4* enc4 = (const float4*)(enc + (size_t)b * L * H) + c;
        float ax = 0.f, ay = 0.f, az = 0.f, aw = 0.f;
#pragma unroll 8
        for (int q = 0; q < 32; ++q) {
            const int lidx = grp * 32 + q;
            const float wv = s_w[lidx];
            float4 ev = enc4[(size_t)lidx * 256];
            ax += wv * ev.x; ay += wv * ev.y; az += wv * ev.z; aw += wv * ev.w;
        }
        if (grp) {
            float4 t; t.x = ax; t.y = ay; t.z = az; t.w = aw;
            s_pac[(grp - 1) * 256 + c] = t;
        }
        __syncthreads();
        if (grp == 0) {
#pragma unroll
            for (int j = 0; j < 3; ++j) {
                float4 t = s_pac[j * 256 + c];
                ax += t.x; ay += t.y; az += t.z; aw += t.w;
            }
            uint2 p;
            p.x = (unsigned)f2bf(ax) | ((unsigned)f2bf(ay) << 16);
            p.y = (unsigned)f2bf(az) | ((unsigned)f2bf(aw) << 16);
            *(uint2*)(xcat_b16 + (size_t)b * 2 * H + H + c * 4) = p;
        }
    }
}

// ---------------------------------------------------------------------------
// bf16 MFMA GEMM core: C = A(256,K bf16) @ W(N,K fp32->bf16).T + bias
// 256 threads (4 waves, each 64 rows x 32 cols).
//  - A prefetch depth 1 (L2-resident, ~200cy, covered by MFMA phase)
//  - W prefetch depth 2 (HBM stream, ~900cy, covered by two phases)
//  - LDS XOR swizzle -> 0 bank conflicts, 36.9 KB -> 4 blocks/CU
//  - Epilogue stages C through LDS and drains with full-128B-line float4
//    stores (8 consecutive lanes per row) to kill partial-line write
//    amplification (was 8.4x: 275 MB HBM writes for 33 MB of logits).
// MODE 0: write fp32      MODE 1: relu + write bf16
// MODE 4: write fp32 logits AND rowsum[r] += sum_col exp(logit) (atomic)
// ---------------------------------------------------------------------------
template<int K, int MODE>
__device__ __forceinline__ void gemm_core(
    ushort* sA, ushort* sW,
    const ushort* __restrict__ A,
    const float* __restrict__ W,
    const float* __restrict__ bias,
    float* __restrict__ outf,
    ushort* __restrict__ outb,
    float* __restrict__ rowsum,
    int N, int bid)
{
    const int tid = threadIdx.x;
    const int bn = bid * 32;
    const int w = tid >> 6;
    const int l = tid & 63;
    const int g = l >> 4;
    const int ln = l & 15;
    const int trow = tid >> 3;   // 0..31
    const int tcol = tid & 7;    // 0..7

    char* sAb = (char*)sA;
    char* sWb = (char*)sW;
    const int wsw = (trow & 7) << 4;   // write swizzle
    const int asw = (ln & 7) << 4;     // read swizzle

    f32x4 acc[4][2];
#pragma unroll
    for (int i = 0; i < 4; ++i)
#pragma unroll
        for (int n = 0; n < 2; ++n)
            acc[i][n] = (f32x4){0.f, 0.f, 0.f, 0.f};

    uint4 pa[8];
    float4 pwa0, pwa1, pwb0, pwb1;
    const ushort* arow = A + (size_t)trow * K + tcol * 8;
    const float* wrow = W + (size_t)(bn + trow) * K + tcol * 8;

    auto LOADA = [&](int k0) {
#pragma unroll
        for (int p = 0; p < 8; ++p)
            pa[p] = *(const uint4*)(arow + (size_t)p * 32 * K + k0);
    };
    auto STOREA = [&]() {
#pragma unroll
        for (int p = 0; p < 8; ++p)
            *(uint4*)(sAb + ((((p * 32 + trow) << 7) + (tcol << 4)) ^ wsw)) = pa[p];
    };
    auto STOREW = [&](float4 w0, float4 w1) {
        ushort t[8];
        t[0] = f2bf(w0.x); t[1] = f2bf(w0.y); t[2] = f2bf(w0.z); t[3] = f2bf(w0.w);
        t[4] = f2bf(w1.x); t[5] = f2bf(w1.y); t[6] = f2bf(w1.z); t[7] = f2bf(w1.w);
        *(uint4*)(sWb + (((trow << 7) + (tcol << 4)) ^ wsw)) = *(const uint4*)t;
    };

    // prologue: A tile 0, W tiles 0 and 64; stage tile 0
    LOADA(0);
    pwa0 = *(const float4*)(wrow + 0);
    pwa1 = *(const float4*)(wrow + 4);
    pwb0 = *(const float4*)(wrow + 64);
    pwb1 = *(const float4*)(wrow + 68);
    STOREA();
    STOREW(pwa0, pwa1);
    __syncthreads();

#pragma unroll
    for (int k0 = 0; k0 < K; k0 += 64) {
        const bool odd = (k0 >> 6) & 1;
        if (k0 + 64 < K) LOADA(k0 + 64);
        if (k0 + 128 < K) {   // refill the W buffer consumed two phases ago
            float4 w0 = *(const float4*)(wrow + k0 + 128);
            float4 w1 = *(const float4*)(wrow + k0 + 132);
            if (odd) { pwb0 = w0; pwb1 = w1; } else { pwa0 = w0; pwa1 = w1; }
        }
        // MFMA on tile k0 (in LDS)
#pragma unroll
        for (int s = 0; s < 2; ++s) {
            bf16x8 af[4], bfr[2];
#pragma unroll
            for (int i = 0; i < 4; ++i)
                af[i] = *(const bf16x8*)(sAb + (((64 * w + 16 * i + ln) << 7) +
                                               ((s * 64 + (g << 4)) ^ asw)));
#pragma unroll
            for (int n = 0; n < 2; ++n)
                bfr[n] = *(const bf16x8*)(sWb + (((16 * n + ln) << 7) +
                                                ((s * 64 + (g << 4)) ^ asw)));
#pragma unroll
            for (int i = 0; i < 4; ++i)
#pragma unroll
                for (int n = 0; n < 2; ++n)
                    acc[i][n] = __builtin_amdgcn_mfma_f32_16x16x32_bf16(af[i], bfr[n], acc[i][n], 0, 0, 0);
        }
        __syncthreads();
        if (k0 + 64 < K) {
            STOREA();                                    // stage A tile k0+64
            STOREW(odd ? pwa0 : pwb0, odd ? pwa1 : pwb1); // stage W tile k0+64
        }
        __syncthreads();
    }

    // ---------------- epilogue: LDS-staged coalesced C writeback ------------
    const float b0 = bias[bn + ln];
    const float b1 = bias[bn + 16 + ln];
    float* sC = (float*)sAb;   // 256 x 32 fp32 = 32 KB (fits in sA)

#pragma unroll
    for (int i = 0; i < 4; ++i)
#pragma unroll
        for (int n = 0; n < 2; ++n)
#pragma unroll
            for (int r = 0; r < 4; ++r) {
                const int row = 64 * w + 16 * i + 4 * g + r;
                float vv = acc[i][n][r] + (n ? b1 : b0);
                if (MODE == 1) vv = fmaxf(vv, 0.f);
                sC[(row << 5) + ((16 * n + ln) ^ ((row & 4) << 2))] = vv;
            }

    if (MODE == 4) {
        // rowsum atomics straight from regs (overlaps the LDS writes)
#pragma unroll
        for (int i = 0; i < 4; ++i) {
            float e[4];
#pragma unroll
            for (int r = 0; r < 4; ++r)
                e[r] = __expf(acc[i][0][r] + b0) + __expf(acc[i][1][r] + b1);
#pragma unroll
            for (int msk = 1; msk < 16; msk <<= 1)
#pragma unroll
                for (int r = 0; r < 4; ++r)
                    e[r] += __shfl_xor(e[r], msk);
            if (ln < 4)
                atomicAdd(&rowsum[64 * w + 16 * i + 4 * g + ln], e[ln]);
        }
    }
    __syncthreads();

    if (MODE == 0 || MODE == 4) {
        // flat drain: 8 lanes cover one row's 32 floats = one full 128B line
#pragma unroll
        for (int it = 0; it < 8; ++it) {
            const int q = it * 256 + tid;
            const int row = q >> 3;
            const int c4 = (q & 7) << 2;
            float4 v = *(const float4*)&sC[(row << 5) + (c4 ^ ((row & 4) << 2))];
            *(float4*)(outf + (size_t)row * N + bn + c4) = v;
        }
    } else {  // MODE 1: bf16 out
#pragma unroll
        for (int it = 0; it < 8; ++it) {
            const int q = it * 256 + tid;
            const int row = q >> 3;
            const int c4 = (q & 7) << 2;
            float4 v = *(const float4*)&sC[(row << 5) + (c4 ^ ((row & 4) << 2))];
            ushort t[4] = {f2bf(v.x), f2bf(v.y), f2bf(v.z), f2bf(v.w)};
            *(uint2*)(outb + (size_t)row * N + bn + c4) = *(const uint2*)t;
        }
    }
}

template<int K, int MODE>
__global__ __launch_bounds__(256, 4) void gemm_kernel(
    const ushort* __restrict__ A,
    const float* __restrict__ W,
    const float* __restrict__ bias,
    float* __restrict__ outf,
    ushort* __restrict__ outb,
    float* __restrict__ rowsum,
    int N)
{
    __shared__ ushort smem[256 * 64 + 32 * 64];
    gemm_core<K, MODE>(smem, smem + 256 * 64, A, W, bias, outf, outb, rowsum, N, blockIdx.x);
}

// comb (K=2048, relu->bf16, 32 blocks) fused with gh (K=1024, fp32, 96 blocks)
__global__ __launch_bounds__(256, 4) void comb_gh_kernel(
    const ushort* __restrict__ xcat,
    const float* __restrict__ comb_w,
    const float* __restrict__ comb_b,
    ushort* __restrict__ x_b16,
    const ushort* __restrict__ h0b,
    const float* __restrict__ w_hh,
    const float* __restrict__ b_hh,
    float* __restrict__ gh)
{
    __shared__ ushort smem[256 * 64 + 32 * 64];
    if (blockIdx.x < 32)
        gemm_core<2 * H, 1>(smem, smem + 256 * 64, xcat, comb_w, comb_b,
                            nullptr, x_b16, nullptr, H, blockIdx.x);
    else
        gemm_core<H, 0>(smem, smem + 256 * 64, h0b, w_hh, b_hh,
                        gh, nullptr, nullptr, 3 * H, blockIdx.x - 32);
}

// ---------------------------------------------------------------------------
// GRU gates; emits h_new fp32+bf16 and zeroes rowsum (block 0).
// ---------------------------------------------------------------------------
__global__ __launch_bounds__(256) void gru_kernel(
    const float* __restrict__ gx,
    const float* __restrict__ gh,
    const float* __restrict__ h0,
    float* __restrict__ h_new,
    ushort* __restrict__ hn_b16,
    float* __restrict__ rowsum)
{
    if (blockIdx.x == 0) rowsum[threadIdx.x] = 0.f;
    const int idx = blockIdx.x * 256 + threadIdx.x;
    const int b = idx >> 10;
    const int j = idx & (H - 1);
    const size_t base = (size_t)b * 3 * H;
    const float xr = gx[base + j];
    const float xz = gx[base + H + j];
    const float xn = gx[base + 2 * H + j];
    const float hr = gh[base + j];
    const float hz = gh[base + H + j];
    const float hn = gh[base + 2 * H + j];
    const float r = 1.f / (1.f + __expf(-(xr + hr)));
    const float z = 1.f / (1.f + __expf(-(xz + hz)));
    const float n = tanhf(xn + r * hn);
    const float out = (1.f - z) * n + z * h0[idx];
    h_new[idx] = out;
    hn_b16[idx] = f2bf(out);
}

// ---------------------------------------------------------------------------
// In-place log-softmax finish: logp[b,v] -= log(rowsum[b])
// ---------------------------------------------------------------------------
__global__ __launch_bounds__(256) void logsm_kernel(
    float* __restrict__ logp,
    const float* __restrict__ rowsum)
{
    __shared__ float s_lse[B];
    if (threadIdx.x < B) s_lse[threadIdx.x] = __logf(rowsum[threadIdx.x]);
    __syncthreads();
    const int total4 = B * V / 4;       // 2,048,000
    for (int i = blockIdx.x * 256 + threadIdx.x; i < total4; i += gridDim.x * 256) {
        float4 v = ((const float4*)logp)[i];
        const int b = i / (V / 4);      // / 8000 -> magic mul
        const float lse = s_lse[b];
        v.x -= lse; v.y -= lse; v.z -= lse; v.w -= lse;
        ((float4*)logp)[i] = v;
    }
}

// ---------------------------------------------------------------------------
extern "C" void kernel_launch(void* const* d_in, const int* in_sizes, int n_in,
                              void* d_out, int out_size, void* d_ws, size_t ws_size,
                              hipStream_t stream) {
    const int*   input_ids = (const int*)d_in[0];
    const float* hidden    = (const float*)d_in[1];
    const float* enc       = (const float*)d_in[2];
    const float* emb_table = (const float*)d_in[3];
    const float* attn_w    = (const float*)d_in[4];
    const float* attn_b    = (const float*)d_in[5];
    const float* comb_w    = (const float*)d_in[6];
    const float* comb_b    = (const float*)d_in[7];
    const float* w_ih      = (const float*)d_in[8];
    const float* b_ih      = (const float*)d_in[9];
    const float* w_hh      = (const float*)d_in[10];
    const float* b_hh      = (const float*)d_in[11];
    const float* out_w     = (const float*)d_in[12];
    const float* out_b     = (const float*)d_in[13];

    float* out = (float*)d_out;
    float* logp         = out;                    // (B, V)
    float* h_new        = out + (size_t)B * V;    // (B, H)
    float* attn_weights = h_new + (size_t)B * H;  // (B, L)

    // workspace layout
    ushort* xcat_b16 = (ushort*)d_ws;                          // B*2H
    ushort* h0_b16   = xcat_b16 + (size_t)B * 2 * H;           // B*H
    ushort* x_b16    = h0_b16 + (size_t)B * H;                 // B*H
    ushort* hn_b16   = x_b16 + (size_t)B * H;                  // B*H
    float*  gx       = (float*)(hn_b16 + (size_t)B * H);       // B*3H
    float*  gh       = gx + (size_t)B * 3 * H;                 // B*3H
    float*  rowsum   = gh + (size_t)B * 3 * H;                 // B

    // 1. attention (+ bf16 casts of emb/attn concat and h0)
    attn_kernel<<<dim3(B), dim3(1024), 0, stream>>>(
        input_ids, hidden, enc, emb_table, attn_w, attn_b,
        xcat_b16, h0_b16, attn_weights);

    // 2. fused: x = relu(xcat @ comb_w.T + comb_b) -> bf16  AND
    //           gh = h0 @ w_hh.T + b_hh
    comb_gh_kernel<<<dim3(32 + 96), dim3(256), 0, stream>>>(
        xcat_b16, comb_w, comb_b, x_b16, h0_b16, w_hh, b_hh, gh);

    // 3. gx = x @ w_ih.T + b_ih   (N=3072)
    gemm_kernel<H, 0><<<dim3(3 * H / 32), dim3(256), 0, stream>>>(
        x_b16, w_ih, b_ih, gx, nullptr, nullptr, 3 * H);

    // 4. GRU gates -> h_new (fp32 + bf16), zero rowsum
    gru_kernel<<<dim3(B * H / 256), dim3(256), 0, stream>>>(
        gx, gh, hidden, h_new, hn_b16, rowsum);

    // 5. single V-GEMM pass: logits -> d_out, rowsum[b] = sum_v exp(logit)
    gemm_kernel<H, 4><<<dim3(V / 32), dim3(256), 0, stream>>>(
        hn_b16, out_w, out_b, logp, nullptr, rowsum, V);

    // 6. in-place: logp -= log(rowsum[b])
    logsm_kernel<<<dim3(2048), dim3(256), 0, stream>>>(logp, rowsum);
}

// Round 4
// 591.049 us; speedup vs baseline: 1.1284x; 1.1284x over previous
//
#include <hip/hip_runtime.h>
#include <hip/hip_bf16.h>
#include <math.h>

#define H 1024
#define L 128
#define B 256
#define V 32000

typedef __attribute__((ext_vector_type(8))) short bf16x8;
typedef __attribute__((ext_vector_type(4))) float f32x4;

static __device__ __forceinline__ ushort f2bf(float f) {
    unsigned int u = __float_as_uint(f);
    u += 0x7fffu + ((u >> 16) & 1u);   // RNE (finite inputs)
    return (ushort)(u >> 16);
}

// ---------------------------------------------------------------------------
// Kernel 1: embedding gather + attention logits + softmax + weighted sum.
// 1024 threads/block (16 waves) for memory-latency hiding on the enc stream.
// ---------------------------------------------------------------------------
__global__ __launch_bounds__(1024) void attn_kernel(
    const int* __restrict__ input_ids,
    const float* __restrict__ hidden,
    const float* __restrict__ enc,
    const float* __restrict__ emb_table,
    const float* __restrict__ attn_w,
    const float* __restrict__ attn_b,
    ushort* __restrict__ xcat_b16,         // (B, 2H) bf16
    ushort* __restrict__ h0_b16,           // (B, H) bf16
    float* __restrict__ attn_weights_out)  // (B, L)
{
    __shared__ float s_e[H];
    __shared__ float s_h[H];
    __shared__ float s_w[L];
    __shared__ float s_r[4];
    __shared__ float4 s_pac[3 * 256];      // 12 KB partial-sum reduce

    const int b = blockIdx.x;
    const int tid = threadIdx.x;

    // load emb row + hidden row into LDS, emit bf16 copies
    if (tid < 256) {
        const int id = input_ids[b];
        float4 ev = ((const float4*)(emb_table + (size_t)id * H))[tid];
        ((float4*)s_e)[tid] = ev;
        uint2 p;
        p.x = (unsigned)f2bf(ev.x) | ((unsigned)f2bf(ev.y) << 16);
        p.y = (unsigned)f2bf(ev.z) | ((unsigned)f2bf(ev.w) << 16);
        *(uint2*)(xcat_b16 + (size_t)b * 2 * H + tid * 4) = p;
    } else if (tid < 512) {
        const int t = tid - 256;
        float4 hv = ((const float4*)(hidden + (size_t)b * H))[t];
        ((float4*)s_h)[t] = hv;
        uint2 q;
        q.x = (unsigned)f2bf(hv.x) | ((unsigned)f2bf(hv.y) << 16);
        q.y = (unsigned)f2bf(hv.z) | ((unsigned)f2bf(hv.w) << 16);
        *(uint2*)(h0_b16 + (size_t)b * H + t * 4) = q;
    }
    __syncthreads();

    // logits: 8 threads per l-row, strided float4 so 8 lanes coalesce to 128B
    {
        const int ll = tid >> 3;   // 0..127
        const int p = tid & 7;
        const float4* wv = (const float4*)(attn_w + (size_t)ll * (2 * H)) + p;
        const float4* se4 = (const float4*)s_e + p;
        const float4* sh4 = (const float4*)s_h + p;
        float acc = 0.f;
#pragma unroll 8
        for (int k = 0; k < 32; ++k) {
            float4 a = wv[k * 8];
            float4 s = se4[k * 8];
            acc += a.x * s.x + a.y * s.y + a.z * s.z + a.w * s.w;
        }
#pragma unroll 8
        for (int k = 0; k < 32; ++k) {
            float4 a = wv[256 + k * 8];
            float4 s = sh4[k * 8];
            acc += a.x * s.x + a.y * s.y + a.z * s.z + a.w * s.w;
        }
        acc += __shfl_xor(acc, 1);
        acc += __shfl_xor(acc, 2);
        acc += __shfl_xor(acc, 4);
        if (p == 0) s_w[ll] = acc + attn_b[ll];
    }
    __syncthreads();

    // softmax over s_w[0..127] (first 2 waves)
    const int lane = tid & 63;
    if (tid < 128) {
        float v = s_w[tid];
        for (int off = 32; off; off >>= 1) v = fmaxf(v, __shfl_xor(v, off));
        if (lane == 0) s_r[tid >> 6] = v;
    }
    __syncthreads();
    if (tid < 128) {
        const float m = fmaxf(s_r[0], s_r[1]);
        float e = __expf(s_w[tid] - m);
        float sv = e;
        for (int off = 32; off; off >>= 1) sv += __shfl_xor(sv, off);
        if (lane == 0) s_r[2 + (tid >> 6)] = sv;
        s_w[tid] = e;
    }
    __syncthreads();
    if (tid < 128) {
        const float inv = 1.f / (s_r[2] + s_r[3]);
        const float wv = s_w[tid] * inv;
        s_w[tid] = wv;
        attn_weights_out[(size_t)b * L + tid] = wv;
    }
    __syncthreads();

    // attn_applied: 4 l-groups x 256 float4 columns, LDS tree reduce
    {
        const int grp = tid >> 8;     // 0..3 -> l range [grp*32, grp*32+32)
        const int c = tid & 255;      // float4 column
        const float4* enc4 = (const float4*)(enc + (size_t)b * L * H) + c;
        float ax = 0.f, ay = 0.f, az = 0.f, aw = 0.f;
#pragma unroll 8
        for (int q = 0; q < 32; ++q) {
            const int lidx = grp * 32 + q;
            const float wv = s_w[lidx];
            float4 ev = enc4[(size_t)lidx * 256];
            ax += wv * ev.x; ay += wv * ev.y; az += wv * ev.z; aw += wv * ev.w;
        }
        if (grp) {
            float4 t; t.x = ax; t.y = ay; t.z = az; t.w = aw;
            s_pac[(grp - 1) * 256 + c] = t;
        }
        __syncthreads();
        if (grp == 0) {
#pragma unroll
            for (int j = 0; j < 3; ++j) {
                float4 t = s_pac[j * 256 + c];
                ax += t.x; ay += t.y; az += t.z; aw += t.w;
            }
            uint2 p;
            p.x = (unsigned)f2bf(ax) | ((unsigned)f2bf(ay) << 16);
            p.y = (unsigned)f2bf(az) | ((unsigned)f2bf(aw) << 16);
            *(uint2*)(xcat_b16 + (size_t)b * 2 * H + H + c * 4) = p;
        }
    }
}

// ---------------------------------------------------------------------------
// Barrier-free streaming MFMA GEMM: C = A(256,K bf16) @ W(N,K fp32).T + bias
// ZERO LDS, ZERO __syncthreads. Both MFMA operands loaded straight from
// global to registers (the 16x16x32 operand lane layout IS row-major):
//   A-frag: lane(g,ln) <- A[row0+16m+ln][k0+32s+8g .. +8]  (1x 16B, L2-hot)
//   B-frag: lane(g,ln) <- W[bn0+16n+ln][k0+32s+8g .. +8]   (2x float4, HBM)
// Register double-buffer of one 64-K macro tile (~4 KB/wave in flight) so
// the HBM stream never drains; compiler emits counted vmcnt waits.
// Block = MT rows x 128 cols (4 waves x 32 cols). Grid (256/MT, N/128).
// MODE 0: fp32 out   MODE 1: relu+bf16 out
// MODE 4: fp32 logits out + rowsum[r] += sum_col exp(logit) (atomic)
// ---------------------------------------------------------------------------
template<int K, int MT, int MODE>
__global__ __launch_bounds__(256, 2) void gemm_stream(
    const ushort* __restrict__ A,
    const float* __restrict__ W,
    const float* __restrict__ bias,
    float* __restrict__ outf,
    ushort* __restrict__ outb,
    float* __restrict__ rowsum,
    int N)
{
    constexpr int MFR = MT / 16;          // m-fragments per wave
    const int tid = threadIdx.x;
    const int wv = tid >> 6;              // wave 0..3 -> n-offset
    const int l  = tid & 63;
    const int g  = l >> 4;                // k-slice group (0..3)
    const int ln = l & 15;                // row/col within fragment

    const int row0 = blockIdx.x * MT;
    const int bn0  = blockIdx.y * 128 + wv * 32;

    const ushort* aptr = A + (size_t)(row0 + ln) * K + g * 8;
    const float*  wptr = W + (size_t)(bn0 + ln) * K + g * 8;

    f32x4 acc[MFR][2];
#pragma unroll
    for (int m = 0; m < MFR; ++m) {
        acc[m][0] = (f32x4){0.f, 0.f, 0.f, 0.f};
        acc[m][1] = (f32x4){0.f, 0.f, 0.f, 0.f};
    }

    bf16x8 aA[MFR][2], aB[MFR][2];        // [m][s]
    float4 wA[2][2][2], wB[2][2][2];      // [n][s][half]

    auto LOADM = [&](bf16x8 (&a)[MFR][2], float4 (&wf)[2][2][2], int k0) {
#pragma unroll
        for (int m = 0; m < MFR; ++m)
#pragma unroll
            for (int s = 0; s < 2; ++s)
                a[m][s] = *(const bf16x8*)(aptr + (size_t)16 * m * K + k0 + 32 * s);
#pragma unroll
        for (int n = 0; n < 2; ++n)
#pragma unroll
            for (int s = 0; s < 2; ++s) {
                const float* p = wptr + (size_t)16 * n * K + k0 + 32 * s;
                wf[n][s][0] = *(const float4*)p;
                wf[n][s][1] = *(const float4*)(p + 4);
            }
    };
    auto COMPUTE = [&](bf16x8 (&a)[MFR][2], float4 (&wf)[2][2][2]) {
#pragma unroll
        for (int s = 0; s < 2; ++s) {
            bf16x8 bw[2];
#pragma unroll
            for (int n = 0; n < 2; ++n) {
                ushort t[8];
                t[0] = f2bf(wf[n][s][0].x); t[1] = f2bf(wf[n][s][0].y);
                t[2] = f2bf(wf[n][s][0].z); t[3] = f2bf(wf[n][s][0].w);
                t[4] = f2bf(wf[n][s][1].x); t[5] = f2bf(wf[n][s][1].y);
                t[6] = f2bf(wf[n][s][1].z); t[7] = f2bf(wf[n][s][1].w);
                bw[n] = *(const bf16x8*)t;
            }
#pragma unroll
            for (int m = 0; m < MFR; ++m)
#pragma unroll
                for (int n = 0; n < 2; ++n)
                    acc[m][n] = __builtin_amdgcn_mfma_f32_16x16x32_bf16(
                        a[m][s], bw[n], acc[m][n], 0, 0, 0);
        }
    };

    // software pipeline, 2 macro-tiles (128 K) per iteration, K % 128 == 0
    LOADM(aA, wA, 0);
    for (int k0 = 0; k0 < K; k0 += 128) {
        LOADM(aB, wB, k0 + 64);
        COMPUTE(aA, wA);
        if (k0 + 128 < K) LOADM(aA, wA, k0 + 128);
        COMPUTE(aB, wB);
    }

    const float b0 = bias[bn0 + ln];
    const float b1 = bias[bn0 + 16 + ln];

    if (MODE == 0) {
#pragma unroll
        for (int m = 0; m < MFR; ++m)
#pragma unroll
            for (int n = 0; n < 2; ++n)
#pragma unroll
                for (int r = 0; r < 4; ++r)
                    outf[(size_t)(row0 + 16 * m + 4 * g + r) * N + bn0 + 16 * n + ln] =
                        acc[m][n][r] + (n ? b1 : b0);
    } else if (MODE == 1) {
#pragma unroll
        for (int m = 0; m < MFR; ++m)
#pragma unroll
            for (int n = 0; n < 2; ++n)
#pragma unroll
                for (int r = 0; r < 4; ++r) {
                    float vv = acc[m][n][r] + (n ? b1 : b0);
                    vv = fmaxf(vv, 0.f);
                    outb[(size_t)(row0 + 16 * m + 4 * g + r) * N + bn0 + 16 * n + ln] = f2bf(vv);
                }
    } else {  // MODE 4
#pragma unroll
        for (int m = 0; m < MFR; ++m) {
            float e[4];
#pragma unroll
            for (int r = 0; r < 4; ++r) {
                const float v0 = acc[m][0][r] + b0;
                const float v1 = acc[m][1][r] + b1;
                const int row = row0 + 16 * m + 4 * g + r;
                outf[(size_t)row * N + bn0 + ln] = v0;
                outf[(size_t)row * N + bn0 + 16 + ln] = v1;
                e[r] = __expf(v0) + __expf(v1);
            }
#pragma unroll
            for (int msk = 1; msk < 16; msk <<= 1)
#pragma unroll
                for (int r = 0; r < 4; ++r)
                    e[r] += __shfl_xor(e[r], msk);
            if (ln < 4)
                atomicAdd(&rowsum[row0 + 16 * m + 4 * g + ln], e[ln]);
        }
    }
}

// ---------------------------------------------------------------------------
// GRU gates; emits h_new fp32+bf16 and zeroes rowsum (block 0).
// ---------------------------------------------------------------------------
__global__ __launch_bounds__(256) void gru_kernel(
    const float* __restrict__ gx,
    const float* __restrict__ gh,
    const float* __restrict__ h0,
    float* __restrict__ h_new,
    ushort* __restrict__ hn_b16,
    float* __restrict__ rowsum)
{
    if (blockIdx.x == 0) rowsum[threadIdx.x] = 0.f;
    const int idx = blockIdx.x * 256 + threadIdx.x;
    const int b = idx >> 10;
    const int j = idx & (H - 1);
    const size_t base = (size_t)b * 3 * H;
    const float xr = gx[base + j];
    const float xz = gx[base + H + j];
    const float xn = gx[base + 2 * H + j];
    const float hr = gh[base + j];
    const float hz = gh[base + H + j];
    const float hn = gh[base + 2 * H + j];
    const float r = 1.f / (1.f + __expf(-(xr + hr)));
    const float z = 1.f / (1.f + __expf(-(xz + hz)));
    const float n = tanhf(xn + r * hn);
    const float out = (1.f - z) * n + z * h0[idx];
    h_new[idx] = out;
    hn_b16[idx] = f2bf(out);
}

// ---------------------------------------------------------------------------
// In-place log-softmax finish: logp[b,v] -= log(rowsum[b])
// ---------------------------------------------------------------------------
__global__ __launch_bounds__(256) void logsm_kernel(
    float* __restrict__ logp,
    const float* __restrict__ rowsum)
{
    __shared__ float s_lse[B];
    if (threadIdx.x < B) s_lse[threadIdx.x] = __logf(rowsum[threadIdx.x]);
    __syncthreads();
    const int total4 = B * V / 4;       // 2,048,000
    for (int i = blockIdx.x * 256 + threadIdx.x; i < total4; i += gridDim.x * 256) {
        float4 v = ((const float4*)logp)[i];
        const int b = i / (V / 4);
        const float lse = s_lse[b];
        v.x -= lse; v.y -= lse; v.z -= lse; v.w -= lse;
        ((float4*)logp)[i] = v;
    }
}

// ---------------------------------------------------------------------------
extern "C" void kernel_launch(void* const* d_in, const int* in_sizes, int n_in,
                              void* d_out, int out_size, void* d_ws, size_t ws_size,
                              hipStream_t stream) {
    const int*   input_ids = (const int*)d_in[0];
    const float* hidden    = (const float*)d_in[1];
    const float* enc       = (const float*)d_in[2];
    const float* emb_table = (const float*)d_in[3];
    const float* attn_w    = (const float*)d_in[4];
    const float* attn_b    = (const float*)d_in[5];
    const float* comb_w    = (const float*)d_in[6];
    const float* comb_b    = (const float*)d_in[7];
    const float* w_ih      = (const float*)d_in[8];
    const float* b_ih      = (const float*)d_in[9];
    const float* w_hh      = (const float*)d_in[10];
    const float* b_hh      = (const float*)d_in[11];
    const float* out_w     = (const float*)d_in[12];
    const float* out_b     = (const float*)d_in[13];

    float* out = (float*)d_out;
    float* logp         = out;                    // (B, V)
    float* h_new        = out + (size_t)B * V;    // (B, H)
    float* attn_weights = h_new + (size_t)B * H;  // (B, L)

    // workspace layout
    ushort* xcat_b16 = (ushort*)d_ws;                          // B*2H
    ushort* h0_b16   = xcat_b16 + (size_t)B * 2 * H;           // B*H
    ushort* x_b16    = h0_b16 + (size_t)B * H;                 // B*H
    ushort* hn_b16   = x_b16 + (size_t)B * H;                  // B*H
    float*  gx       = (float*)(hn_b16 + (size_t)B * H);       // B*3H
    float*  gh       = gx + (size_t)B * 3 * H;                 // B*3H
    float*  rowsum   = gh + (size_t)B * 3 * H;                 // B

    // 1. attention (+ bf16 casts of emb/attn concat and h0)
    attn_kernel<<<dim3(B), dim3(1024), 0, stream>>>(
        input_ids, hidden, enc, emb_table, attn_w, attn_b,
        xcat_b16, h0_b16, attn_weights);

    // 2. gh = h0 @ w_hh.T + b_hh          (16x24 = 384 blocks)
    gemm_stream<H, 16, 0><<<dim3(16, 24), dim3(256), 0, stream>>>(
        h0_b16, w_hh, b_hh, gh, nullptr, nullptr, 3 * H);

    // 3. x = relu(xcat @ comb_w.T + comb_b) -> bf16   (16x8 = 128 blocks)
    gemm_stream<2 * H, 16, 1><<<dim3(16, 8), dim3(256), 0, stream>>>(
        xcat_b16, comb_w, comb_b, nullptr, x_b16, nullptr, H);

    // 4. gx = x @ w_ih.T + b_ih           (16x24 = 384 blocks)
    gemm_stream<H, 16, 0><<<dim3(16, 24), dim3(256), 0, stream>>>(
        x_b16, w_ih, b_ih, gx, nullptr, nullptr, 3 * H);

    // 5. GRU gates -> h_new (fp32 + bf16), zero rowsum
    gru_kernel<<<dim3(B * H / 256), dim3(256), 0, stream>>>(
        gx, gh, hidden, h_new, hn_b16, rowsum);

    // 6. V-GEMM: logits -> d_out, rowsum[b] = sum_v exp(logit)  (4x250 blocks)
    gemm_stream<H, 64, 4><<<dim3(4, 250), dim3(256), 0, stream>>>(
        hn_b16, out_w, out_b, logp, nullptr, rowsum, V);

    // 7. in-place: logp -= log(rowsum[b])
    logsm_kernel<<<dim3(2048), dim3(256), 0, stream>>>(logp, rowsum);
}